// Round 13
// baseline (361.406 us; speedup 1.0000x reference)
//
#include <hip/hip_runtime.h>
#include <hip/hip_bf16.h>

#define N_NODES 30000
#define F_INLEN 500
#define HID 16
#define OUTC 3
#define NEDGE 960000
#define YP 16                   // shorts per yh row: 32B rows, 16B-aligned
#define NBIN 938                // bins of 32 nodes: 938*32 = 30016 >= 30000
#define HBLK 128                // hist blocks (K0) and scatter riders (K1)
#define EPRH (NEDGE / HBLK)     // 7500 edges per hist/scatter block
#define ECAPS 1280              // per-bin storage capacity (mean 1024, +8 sigma)
#define ECAP 1536               // agg1 LDS sort buffer capacity

typedef float  f32x4 __attribute__((ext_vector_type(4)));
typedef float  f32x2 __attribute__((ext_vector_type(2)));
typedef short  s16x8 __attribute__((ext_vector_type(8)));

static __device__ __forceinline__ unsigned short f2bf(float f) {
    unsigned int u = __float_as_uint(f);
    unsigned int r = (u + 0x7fffu + ((u >> 16) & 1u)) >> 16;
    return (unsigned short)r;
}
static __device__ __forceinline__ unsigned int pack_bf16x2(float v0, float v1) {
#if __has_builtin(__builtin_amdgcn_cvt_pk_bf16_f32)
    typedef __bf16 bf16x2_t __attribute__((ext_vector_type(2)));
    union { bf16x2_t v; unsigned int u; } cv;
    cv.v = __builtin_amdgcn_cvt_pk_bf16_f32(v0, v1);
    return cv.u;
#else
    return __builtin_amdgcn_perm(__float_as_uint(v1), __float_as_uint(v0), 0x07060302);
#endif
}

// ---------------- K0: [0..127] degi histogram; [128] B-fragments -------------
__global__ __launch_bounds__(256) void hist_kernel(
    const float* __restrict__ w2, short* __restrict__ bfragsG,
    const int* __restrict__ dst, int* __restrict__ degi)
{
    const int tid = threadIdx.x;
    if (blockIdx.x == HBLK) {   // bfrag block
        if (tid < 64) {
            const int n16 = tid & 15, q = tid >> 4;
#pragma unroll
            for (int j = 0; j < 8; j++) {
                {   // s = 0
                    const int c = q * 8 + j;
                    const int t = c >> 4, i = c & 15;
                    bfragsG[tid * 16 + j] = (short)f2bf(w2[n16 * 48 + i * 3 + t]);
                }
                {   // s = 1 (zero for c >= 48)
                    const int c = 32 + q * 8 + j;
                    short v = 0;
                    if (c < 48) { const int t = c >> 4, i = c & 15; v = (short)f2bf(w2[n16 * 48 + i * 3 + t]); }
                    bfragsG[tid * 16 + 8 + j] = v;
                }
            }
        }
        return;
    }
    const int e0 = blockIdx.x * EPRH;
    for (int e = e0 + tid; e < e0 + EPRH; e += 256) {
        atomicAdd(&degi[dst[e]], 1);
    }
}

// ---------------- K1: [blocks 0..127] scatter riders  [128..30127] conv ------
// Riders: direct scatter into fixed-capacity bins — no scan, no barriers:
//   pos = atomicAdd(&bincur[bin], 1); packed[bin*ECAPS + pos] = src | d<<15.
// Conv: conv1->relu->conv2(MFMA)->relu->max, epilogue prescaled by rsqrt(deg+1).
__global__ __launch_bounds__(256, 8) void conv_reorder(
    const float* __restrict__ x,
    const float* __restrict__ w1, const float* __restrict__ b1,
    const float* __restrict__ b2, const short* __restrict__ bfragsG,
    const int* __restrict__ src, const int* __restrict__ dst,
    const int* __restrict__ degi, int* __restrict__ bincur,
    int* __restrict__ packed, float* __restrict__ h0)
{
    __shared__ __align__(16) unsigned short yh[516 * YP];   // 16512 B
    __shared__ __align__(16) float xp[502];
    __shared__ float red[64];

    const int tid = threadIdx.x;

    if (blockIdx.x < HBLK) {
        const int e0 = blockIdx.x * EPRH;
        for (int e = e0 + tid; e < e0 + EPRH; e += 256) {
            const int d = dst[e];
            const int b = d >> 5;
            const int pos = atomicAdd(&bincur[b], 1);
            packed[b * ECAPS + pos] = src[e] | (d << 15);
        }
        return;
    }

    const int node = blockIdx.x - HBLK;
    const int dgi  = degi[node];            // uniform -> s_load, issued early
    const int lane = tid & 63;
    const int wave = tid >> 6;
    const int n16  = lane & 15;
    const int q    = lane >> 4;

    if (tid == 0) { xp[0] = 0.f; xp[501] = 0.f; }
    if (tid < 125) {
        const float4 v = ((const float4*)(x + (long long)node * F_INLEN))[tid];
        xp[4 * tid + 1] = v.x; xp[4 * tid + 2] = v.y;
        xp[4 * tid + 3] = v.z; xp[4 * tid + 4] = v.w;
    }
    {
        const int ri = tid >> 4;
        const int row = (ri == 0) ? 0 : (500 + ri);
        yh[row * YP + (tid & 15)] = 0;
    }
    const s16x8* bfp = (const s16x8*)(bfragsG + lane * 16);
    const s16x8 bh0 = bfp[0], bh1 = bfp[1];

    // wt* stay SGPR (one scalar operand per pk-fma); bbv hoisted to fma addend
    f32x2 wt0[8], wt1[8], wt2[8], bbv[8];
#pragma unroll
    for (int cp = 0; cp < 8; cp++) {
        const int c0 = 2 * cp, c1 = 2 * cp + 1;
        wt0[cp] = (f32x2){w1[c0 * 3 + 0], w1[c1 * 3 + 0]};
        wt1[cp] = (f32x2){w1[c0 * 3 + 1], w1[c1 * 3 + 1]};
        wt2[cp] = (f32x2){w1[c0 * 3 + 2], w1[c1 * 3 + 2]};
        bbv[cp] = (f32x2){b1[c0], b1[c1]};
    }
    __syncthreads();

    for (int p = tid; p < 500; p += 256) {
        const float x0 = xp[p], x1 = xp[p + 1], x2 = xp[p + 2];
        const f32x2 xv0 = {x0, x0}, xv1 = {x1, x1}, xv2 = {x2, x2};
        const f32x2 zero = {0.f, 0.f};
        unsigned int hp[8];
#pragma unroll
        for (int cp = 0; cp < 8; cp++) {
            f32x2 a = __builtin_elementwise_fma(wt0[cp], xv0, bbv[cp]);
            a = __builtin_elementwise_fma(wt1[cp], xv1, a);
            a = __builtin_elementwise_fma(wt2[cp], xv2, a);
            a = __builtin_elementwise_max(a, zero);
            hp[cp] = pack_bf16x2(a[0], a[1]);
        }
        uint4* d = (uint4*)&yh[(p + 1) * YP];
        d[0] = make_uint4(hp[0], hp[1], hp[2], hp[3]);
        d[1] = make_uint4(hp[4], hp[5], hp[6], hp[7]);
    }
    __syncthreads();

    // A-fragment base: row = tile*16 + n16 + tap(q>>1), col-half = q&1.
    // tile stride = 16 rows * 32B = 512B (imm); ah1 sits +2 rows = +32 shorts.
    const unsigned short* ybase = yh + (n16 + (q >> 1)) * YP + (q & 1) * 8
                                     + wave * (8 * 16 * YP);
    f32x4 mxv = {-3.0e38f, -3.0e38f, -3.0e38f, -3.0e38f};
    f32x4 mxt = {-3.0e38f, -3.0e38f, -3.0e38f, -3.0e38f};
#pragma unroll
    for (int it = 0; it < 8; it++) {
        const s16x8 ah0 = *(const s16x8*)(ybase + it * (16 * YP));
        const s16x8 ah1 = *(const s16x8*)(ybase + it * (16 * YP) + 2 * YP);
        f32x4 acc = {0.f, 0.f, 0.f, 0.f};
        acc = __builtin_amdgcn_mfma_f32_16x16x32_bf16(ah0, bh0, acc, 0, 0, 0);
        acc = __builtin_amdgcn_mfma_f32_16x16x32_bf16(ah1, bh1, acc, 0, 0, 0);
        if (it < 7) mxv = __builtin_elementwise_max(mxv, acc);
        else        mxt = __builtin_elementwise_max(mxt, acc);
    }
    // last tile (it==7): tiles 7/15/23 fully valid; tile 31 valid only for q==0
    if (wave < 3 || q == 0) mxv = __builtin_elementwise_max(mxv, mxt);
    float m = fmaxf(fmaxf(mxv[0], mxv[1]), fmaxf(mxv[2], mxv[3]));
    m = fmaxf(m, __shfl_xor(m, 16));
    m = fmaxf(m, __shfl_xor(m, 32));
    if (lane < 16) red[wave * 16 + lane] = m;
    __syncthreads();
    if (tid < 16) {
        const float mm = fmaxf(fmaxf(red[tid], red[16 + tid]), fmaxf(red[32 + tid], red[48 + tid]));
        const float dv = rsqrtf((float)(dgi + 1));
        h0[node * HID + tid] = fmaxf(mm + b2[tid], 0.f) * dv;
    }
}

// ---------------- K2: agg layer 1 + W1 + relu + W2; emits sorted packed ------
// Bin blk occupies packed[blk*ECAPS .. +cnt); per-node counts from degi.
// t2p4[node] = (t2p.x, t2p.y, t2p.z, dv); binofs[blk*64+{0..31:start,32..63:count}]
__global__ __launch_bounds__(512) void agg1_kernel(
    int* __restrict__ packed, const float* __restrict__ h0,
    const int* __restrict__ degi,
    const float* __restrict__ W1, const float* __restrict__ b1g,
    const float* __restrict__ W2, float4* __restrict__ t2p4,
    int* __restrict__ binofs)
{
    __shared__ float w1s[256];
    __shared__ float w2s[48];
    __shared__ float b1s[16];
    __shared__ float accS[32 * 17];
    __shared__ int srt[ECAP];
    __shared__ int h32[32], ls32[32], lofs32[32];
    const int tid = threadIdx.x;
    const int blk = blockIdx.x;
    if (tid < 256) w1s[tid] = W1[tid];
    if (tid < 48) w2s[tid] = W2[tid];
    if (tid < 16) b1s[tid] = b1g[tid];
    if (tid < 32) {
        const int nd = blk * 32 + tid;
        const int v = (nd < N_NODES) ? degi[nd] : 0;   // == count within bin
        h32[tid] = v;
        int inc = v;
#pragma unroll
        for (int off = 1; off < 32; off <<= 1) {
            const int y = __shfl_up(inc, off);
            if (tid >= off) inc += y;
        }
        ls32[tid] = inc - v;
        lofs32[tid] = inc - v;
    }
    const int beg = blk * ECAPS;
    __syncthreads();
    const int cnt = ls32[31] + h32[31];
    // node-sort scatter: read packed from global (coalesced), place into srt
    for (int j = tid; j < cnt; j += 512) {
        const int p = packed[beg + j];
        const int pos = atomicAdd(&lofs32[(p >> 15) & 31], 1);
        srt[pos] = p;
    }
    __syncthreads();
    // writeback sorted edges + per-node offsets for agg2 (coalesced)
    for (int j = tid; j < cnt; j += 512) packed[beg + j] = srt[j];
    if (tid < 32) {
        binofs[blk * 64 + tid]      = ls32[tid];
        binofs[blk * 64 + 32 + tid] = h32[tid];
    }
    // gather: 16 threads/node -> n = tid>>4, eslot = (tid>>2)&3, q = tid&3
    const int n = tid >> 4;
    const int eslot = (tid >> 2) & 3;
    const int q = tid & 3;
    const int node = blk * 32 + n;
    const bool valid = node < N_NODES;
    f32x4 acc = {0.f, 0.f, 0.f, 0.f};
    if (valid) {
        const int s0 = ls32[n];
        const int s1 = s0 + h32[n];
        for (int i = s0 + eslot; i < s1; i += 4) {
            const int s = srt[i] & 32767;
            acc += *(const f32x4*)(h0 + s * HID + q * 4);
        }
    }
#pragma unroll
    for (int c = 0; c < 4; c++) {
        acc[c] += __shfl_xor(acc[c], 4);
        acc[c] += __shfl_xor(acc[c], 8);
    }
    if (valid && eslot == 0) {
        acc += *(const f32x4*)(h0 + node * HID + q * 4);   // self (prescaled)
        accS[n * 17 + q * 4 + 0] = acc[0];
        accS[n * 17 + q * 4 + 1] = acc[1];
        accS[n * 17 + q * 4 + 2] = acc[2];
        accS[n * 17 + q * 4 + 3] = acc[3];
    }
    __syncthreads();
    if (tid < 128) {
        const int n2 = tid >> 2;
        const int node2 = blk * 32 + n2;
        if (node2 < N_NODES) {
            const float dv = rsqrtf((float)(h32[n2] + 1));
            const int q2 = tid & 3;
            float y0 = 0.f, y1 = 0.f, y2 = 0.f, y3 = 0.f;
#pragma unroll
            for (int i = 0; i < 16; i++) {
                const float a = accS[n2 * 17 + i];
                y0 = fmaf(a, w1s[i * 16 + q2 * 4 + 0], y0);
                y1 = fmaf(a, w1s[i * 16 + q2 * 4 + 1], y1);
                y2 = fmaf(a, w1s[i * 16 + q2 * 4 + 2], y2);
                y3 = fmaf(a, w1s[i * 16 + q2 * 4 + 3], y3);
            }
            float d0 = 0.f, d1 = 0.f, d2 = 0.f;
            const float yv[4] = {y0, y1, y2, y3};
#pragma unroll
            for (int j = 0; j < 4; j++) {
                const int o = q2 * 4 + j;
                const float h = fmaxf(b1s[o] + dv * yv[j], 0.f);
                d0 = fmaf(h, w2s[o * 3 + 0], d0);
                d1 = fmaf(h, w2s[o * 3 + 1], d1);
                d2 = fmaf(h, w2s[o * 3 + 2], d2);
            }
            d0 += __shfl_xor(d0, 1); d0 += __shfl_xor(d0, 2);
            d1 += __shfl_xor(d1, 1); d1 += __shfl_xor(d1, 2);
            d2 += __shfl_xor(d2, 1); d2 += __shfl_xor(d2, 2);
            if (q2 == 0) t2p4[node2] = make_float4(d0 * dv, d1 * dv, d2 * dv, dv);
        }
    }
}

// ---------------- K3: agg layer 2 (pre-sorted) + log_softmax -----------------
// 512 threads: 16 lanes/node; gather reads packed directly from global
// (per-node edges contiguous -> 64B coalesced lines), no LDS staging.
__global__ __launch_bounds__(512) void agg2_kernel(
    const int* __restrict__ packed, const float4* __restrict__ t2p4,
    const int* __restrict__ binofs, const float* __restrict__ b2g,
    float* __restrict__ out)
{
    __shared__ int ofs[64];
    const int tid = threadIdx.x;
    const int blk = blockIdx.x;
    const int beg = blk * ECAPS;
    if (tid < 64) ofs[tid] = binofs[blk * 64 + tid];
    __syncthreads();
    const int n = tid >> 4;
    const int ln16 = tid & 15;
    const int node = blk * 32 + n;
    float a0 = 0.f, a1 = 0.f, a2 = 0.f;
    if (node < N_NODES) {
        const int s0 = ofs[n];
        const int s1 = s0 + ofs[32 + n];
        for (int i = s0 + ln16; i < s1; i += 16) {
            const int s = packed[beg + i] & 32767;
            const float4 v = t2p4[s];
            a0 += v.x; a1 += v.y; a2 += v.z;
        }
    }
#pragma unroll
    for (int msk = 1; msk < 16; msk <<= 1) {
        a0 += __shfl_xor(a0, msk);
        a1 += __shfl_xor(a1, msk);
        a2 += __shfl_xor(a2, msk);
    }
    if (ln16 == 0 && node < N_NODES) {
        const float4 self = t2p4[node];
        const float dv = self.w;
        const float z0 = b2g[0] + dv * (a0 + self.x);
        const float z1 = b2g[1] + dv * (a1 + self.y);
        const float z2 = b2g[2] + dv * (a2 + self.z);
        const float m = fmaxf(z0, fmaxf(z1, z2));
        const float lg = m + logf(expf(z0 - m) + expf(z1 - m) + expf(z2 - m));
        out[node * 3 + 0] = z0 - lg;
        out[node * 3 + 1] = z1 - lg;
        out[node * 3 + 2] = z2 - lg;
    }
}

extern "C" void kernel_launch(void* const* d_in, const int* in_sizes, int n_in,
                              void* d_out, int out_size, void* d_ws, size_t ws_size,
                              hipStream_t stream)
{
    const float* x   = (const float*)d_in[0];
    const float* w1  = (const float*)d_in[1];
    const float* b1  = (const float*)d_in[2];
    const float* w2  = (const float*)d_in[3];
    const float* b2  = (const float*)d_in[4];
    const float* g1w = (const float*)d_in[5];
    const float* g1b = (const float*)d_in[6];
    const float* g2w = (const float*)d_in[7];
    const float* g2b = (const float*)d_in[8];
    const int*   ei  = (const int*)d_in[9];
    const int* src = ei;
    const int* dst = ei + NEDGE;

    float* ws = (float*)d_ws;
    float*  h0      = ws;                       // 480000 f (prescaled at write)
    float4* t2p4    = (float4*)(ws + 480000);   // 30000 float4 (16B aligned)
    int*    degi    = (int*)(ws + 600000);      // 30000 i
    int*    bincur  = (int*)(ws + 630000);      // 938 i (pad to 960)
    int*    packed  = (int*)(ws + 630960);      // 938*1280 = 1200640 i
    int*    binofs  = (int*)(ws + 1831600);     // 938*64 = 60032 i
    short*  bfragsG = (short*)(ws + 1891632);   // 1024 s
    float*  out     = (float*)d_out;

    hipMemsetAsync(degi, 0, (N_NODES + 960) * sizeof(int), stream);  // degi+bincur
    hist_kernel<<<HBLK + 1, 256, 0, stream>>>(w2, bfragsG, dst, degi);
    conv_reorder<<<HBLK + N_NODES, 256, 0, stream>>>(x, w1, b1, b2, bfragsG,
                                                     src, dst, degi, bincur,
                                                     packed, h0);
    agg1_kernel<<<NBIN, 512, 0, stream>>>(packed, h0, degi,
                                          g1w, g1b, g2w, t2p4, binofs);
    agg2_kernel<<<NBIN, 512, 0, stream>>>(packed, t2p4, binofs, g2b, out);
}

// Round 14
// 213.482 us; speedup vs baseline: 1.6929x; 1.6929x over previous
//
#include <hip/hip_runtime.h>
#include <hip/hip_bf16.h>

#define N_NODES 30000
#define F_INLEN 500
#define HID 16
#define OUTC 3
#define NEDGE 960000
#define YP 16                   // shorts per yh row: 32B rows, 16B-aligned
#define NBIN 938                // bins of 32 nodes: 938*32 = 30016 >= 30000
#define HBLK 128                // hist blocks (K0) and reorder riders (K1)
#define EPRH (NEDGE / HBLK)     // 7500 edges per hist/reorder block
#define ECAP 1536               // per-bin edge capacity (mean 1024, max ~1180)

typedef float  f32x4 __attribute__((ext_vector_type(4)));
typedef float  f32x2 __attribute__((ext_vector_type(2)));
typedef short  s16x8 __attribute__((ext_vector_type(8)));

static __device__ __forceinline__ unsigned short f2bf(float f) {
    unsigned int u = __float_as_uint(f);
    unsigned int r = (u + 0x7fffu + ((u >> 16) & 1u)) >> 16;
    return (unsigned short)r;
}
static __device__ __forceinline__ unsigned int pack_bf16x2(float v0, float v1) {
#if __has_builtin(__builtin_amdgcn_cvt_pk_bf16_f32)
    typedef __bf16 bf16x2_t __attribute__((ext_vector_type(2)));
    union { bf16x2_t v; unsigned int u; } cv;
    cv.v = __builtin_amdgcn_cvt_pk_bf16_f32(v0, v1);
    return cv.u;
#else
    return __builtin_amdgcn_perm(__float_as_uint(v1), __float_as_uint(v0), 0x07060302);
#endif
}

// ---------------- K0: [0..127] bin hist + degi; [128] B-fragments ------------
// 512 threads: halves the per-thread trip count of this 0.5-blocks/CU
// latency-bound kernel; algorithm and outputs identical.
__global__ __launch_bounds__(512) void hist_kernel(
    const float* __restrict__ w2, short* __restrict__ bfragsG,
    const int* __restrict__ dst, int* __restrict__ degi, int* __restrict__ cntbase)
{
    const int tid = threadIdx.x;
    if (blockIdx.x == HBLK) {   // bfrag block
        if (tid < 64) {
            const int n16 = tid & 15, q = tid >> 4;
#pragma unroll
            for (int j = 0; j < 8; j++) {
                {   // s = 0
                    const int c = q * 8 + j;
                    const int t = c >> 4, i = c & 15;
                    bfragsG[tid * 16 + j] = (short)f2bf(w2[n16 * 48 + i * 3 + t]);
                }
                {   // s = 1 (zero for c >= 48)
                    const int c = 32 + q * 8 + j;
                    short v = 0;
                    if (c < 48) { const int t = c >> 4, i = c & 15; v = (short)f2bf(w2[n16 * 48 + i * 3 + t]); }
                    bfragsG[tid * 16 + 8 + j] = v;
                }
            }
        }
        return;
    }
    __shared__ int histH[NBIN];
    for (int i = tid; i < NBIN; i += 512) histH[i] = 0;
    __syncthreads();
    const int e0 = blockIdx.x * EPRH;
    for (int e = e0 + tid; e < e0 + EPRH; e += 512) {
        const int d = dst[e];
        atomicAdd(&histH[d >> 5], 1);
        atomicAdd(&degi[d], 1);
    }
    __syncthreads();
    for (int i = tid; i < NBIN; i += 512) cntbase[blockIdx.x * NBIN + i] = histH[i];
}

// ---------------- K1: [blocks 0..127] reorder riders  [128..30127] conv ------
// Riders: per-bin scan of cntbase -> binstart; direct global scatter of edges.
// Conv: conv1->relu->conv2(MFMA)->relu->max, epilogue prescaled by rsqrt(deg+1).
// yh rows are 32B (16B-aligned): b128 LDS ops + immediate tile offsets.
__global__ __launch_bounds__(256, 8) void conv_reorder(
    const float* __restrict__ x,
    const float* __restrict__ w1, const float* __restrict__ b1,
    const float* __restrict__ b2, const short* __restrict__ bfragsG,
    const int* __restrict__ src, const int* __restrict__ dst,
    const int* __restrict__ degi, const int* __restrict__ cntbase,
    int* __restrict__ packed, int* __restrict__ binstart,
    float* __restrict__ h0)
{
    __shared__ __align__(16) unsigned short yh[516 * YP];   // 16512 B
    __shared__ __align__(16) float xp[502];
    __shared__ float red[64];

    const int tid = threadIdx.x;

    if (blockIdx.x < HBLK) {
        // ---- reorder rider: LDS aliased onto conv's yh (disjoint paths) ----
        int* scA    = (int*)yh;                 // 938
        int* scB    = scA + NBIN;               // 938
        int* totb   = scB + NBIN;               // 938
        int* cursor = totb + NBIN;              // 938  (total 15008 B < 16512)
        const int blk = blockIdx.x;
        for (int bin = tid; bin < NBIN; bin += 256) {
            int tot = 0, psum = 0;
            for (int k = 0; k < HBLK; k++) {
                const int c = cntbase[k * NBIN + bin];
                tot += c;
                if (k < blk) psum += c;
            }
            scA[bin]    = tot;
            totb[bin]   = tot;
            cursor[bin] = psum;
        }
        __syncthreads();
        int* pA = scA; int* pB = scB;
        for (int off = 1; off < NBIN; off <<= 1) {
            for (int i = tid; i < NBIN; i += 256)
                pB[i] = pA[i] + ((i >= off) ? pA[i - off] : 0);
            __syncthreads();
            int* tp = pA; pA = pB; pB = tp;
        }
        for (int i = tid; i < NBIN; i += 256) {
            const int excl = pA[i] - totb[i];
            cursor[i] += excl;
            if (blk == 0) binstart[i] = excl;
        }
        if (blk == 0 && tid == 0) binstart[NBIN] = NEDGE;
        __syncthreads();
        const int e0 = blk * EPRH;
        for (int e = e0 + tid; e < e0 + EPRH; e += 256) {
            const int d = dst[e];
            const int pos = atomicAdd(&cursor[d >> 5], 1);
            packed[pos] = src[e] | (d << 15);
        }
        return;
    }

    const int node = blockIdx.x - HBLK;
    const int dgi  = degi[node];            // uniform -> s_load, issued early
    const int lane = tid & 63;
    const int wave = tid >> 6;
    const int n16  = lane & 15;
    const int q    = lane >> 4;

    if (tid == 0) { xp[0] = 0.f; xp[501] = 0.f; }
    if (tid < 125) {
        const float4 v = ((const float4*)(x + (long long)node * F_INLEN))[tid];
        xp[4 * tid + 1] = v.x; xp[4 * tid + 2] = v.y;
        xp[4 * tid + 3] = v.z; xp[4 * tid + 4] = v.w;
    }
    {
        const int ri = tid >> 4;
        const int row = (ri == 0) ? 0 : (500 + ri);
        yh[row * YP + (tid & 15)] = 0;
    }
    const s16x8* bfp = (const s16x8*)(bfragsG + lane * 16);
    const s16x8 bh0 = bfp[0], bh1 = bfp[1];

    // wt* stay SGPR (one scalar operand per pk-fma); bbv hoisted to fma addend
    f32x2 wt0[8], wt1[8], wt2[8], bbv[8];
#pragma unroll
    for (int cp = 0; cp < 8; cp++) {
        const int c0 = 2 * cp, c1 = 2 * cp + 1;
        wt0[cp] = (f32x2){w1[c0 * 3 + 0], w1[c1 * 3 + 0]};
        wt1[cp] = (f32x2){w1[c0 * 3 + 1], w1[c1 * 3 + 1]};
        wt2[cp] = (f32x2){w1[c0 * 3 + 2], w1[c1 * 3 + 2]};
        bbv[cp] = (f32x2){b1[c0], b1[c1]};
    }
    __syncthreads();

    for (int p = tid; p < 500; p += 256) {
        const float x0 = xp[p], x1 = xp[p + 1], x2 = xp[p + 2];
        const f32x2 xv0 = {x0, x0}, xv1 = {x1, x1}, xv2 = {x2, x2};
        const f32x2 zero = {0.f, 0.f};
        unsigned int hp[8];
#pragma unroll
        for (int cp = 0; cp < 8; cp++) {
            f32x2 a = __builtin_elementwise_fma(wt0[cp], xv0, bbv[cp]);
            a = __builtin_elementwise_fma(wt1[cp], xv1, a);
            a = __builtin_elementwise_fma(wt2[cp], xv2, a);
            a = __builtin_elementwise_max(a, zero);
            hp[cp] = pack_bf16x2(a[0], a[1]);
        }
        uint4* d = (uint4*)&yh[(p + 1) * YP];
        d[0] = make_uint4(hp[0], hp[1], hp[2], hp[3]);
        d[1] = make_uint4(hp[4], hp[5], hp[6], hp[7]);
    }
    __syncthreads();

    // A-fragment base: row = tile*16 + n16 + tap(q>>1), col-half = q&1.
    // tile stride = 16 rows * 32B = 512B (imm); ah1 sits +2 rows = +32 shorts.
    const unsigned short* ybase = yh + (n16 + (q >> 1)) * YP + (q & 1) * 8
                                     + wave * (8 * 16 * YP);
    f32x4 mxv = {-3.0e38f, -3.0e38f, -3.0e38f, -3.0e38f};
    f32x4 mxt = {-3.0e38f, -3.0e38f, -3.0e38f, -3.0e38f};
#pragma unroll
    for (int it = 0; it < 8; it++) {
        const s16x8 ah0 = *(const s16x8*)(ybase + it * (16 * YP));
        const s16x8 ah1 = *(const s16x8*)(ybase + it * (16 * YP) + 2 * YP);
        f32x4 acc = {0.f, 0.f, 0.f, 0.f};
        acc = __builtin_amdgcn_mfma_f32_16x16x32_bf16(ah0, bh0, acc, 0, 0, 0);
        acc = __builtin_amdgcn_mfma_f32_16x16x32_bf16(ah1, bh1, acc, 0, 0, 0);
        if (it < 7) mxv = __builtin_elementwise_max(mxv, acc);
        else        mxt = __builtin_elementwise_max(mxt, acc);
    }
    // last tile (it==7): tiles 7/15/23 fully valid; tile 31 valid only for q==0
    if (wave < 3 || q == 0) mxv = __builtin_elementwise_max(mxv, mxt);
    float m = fmaxf(fmaxf(mxv[0], mxv[1]), fmaxf(mxv[2], mxv[3]));
    m = fmaxf(m, __shfl_xor(m, 16));
    m = fmaxf(m, __shfl_xor(m, 32));
    if (lane < 16) red[wave * 16 + lane] = m;
    __syncthreads();
    if (tid < 16) {
        const float mm = fmaxf(fmaxf(red[tid], red[16 + tid]), fmaxf(red[32 + tid], red[48 + tid]));
        const float dv = rsqrtf((float)(dgi + 1));
        h0[node * HID + tid] = fmaxf(mm + b2[tid], 0.f) * dv;
    }
}

// ---------------- K2: agg layer 1 + W1 + relu + W2; emits sorted packed ------
// 512 threads: 16 threads/node on the gather (4 eslots x 4 q), 2x waves/CU.
// t2p4[node] = (t2p.x, t2p.y, t2p.z, dv); binofs[blk*64+{0..31:start,32..63:count}]
__global__ __launch_bounds__(512) void agg1_kernel(
    const int* __restrict__ binstart, int* __restrict__ packed,
    const float* __restrict__ h0,
    const float* __restrict__ W1, const float* __restrict__ b1g,
    const float* __restrict__ W2, float4* __restrict__ t2p4,
    int* __restrict__ binofs)
{
    __shared__ float w1s[256];
    __shared__ float w2s[48];
    __shared__ float b1s[16];
    __shared__ float accS[32 * 17];
    __shared__ int eL[ECAP];
    __shared__ int srt[ECAP];
    __shared__ int h32[32], ls32[32], lofs32[32];
    const int tid = threadIdx.x;
    const int blk = blockIdx.x;
    if (tid < 256) w1s[tid] = W1[tid];
    if (tid < 48) w2s[tid] = W2[tid];
    if (tid < 16) b1s[tid] = b1g[tid];
    if (tid < 32) h32[tid] = 0;
    const int beg = binstart[blk];
    const int cnt = binstart[blk + 1] - beg;
    __syncthreads();
    for (int j = tid; j < cnt; j += 512) {
        const int p = packed[beg + j];
        eL[j] = p;
        atomicAdd(&h32[(p >> 15) & 31], 1);
    }
    __syncthreads();
    if (tid < 32) {
        const int v = h32[tid];
        int inc = v;
#pragma unroll
        for (int off = 1; off < 32; off <<= 1) {
            const int y = __shfl_up(inc, off);
            if (tid >= off) inc += y;
        }
        ls32[tid] = inc - v;
        lofs32[tid] = inc - v;
    }
    __syncthreads();
    for (int j = tid; j < cnt; j += 512) {
        const int p = eL[j];
        const int pos = atomicAdd(&lofs32[(p >> 15) & 31], 1);
        srt[pos] = p;
    }
    __syncthreads();
    // writeback sorted edges + per-node offsets for agg2 (coalesced)
    for (int j = tid; j < cnt; j += 512) packed[beg + j] = srt[j];
    if (tid < 32) {
        binofs[blk * 64 + tid]      = ls32[tid];
        binofs[blk * 64 + 32 + tid] = h32[tid];
    }
    // gather: 16 threads/node -> n = tid>>4, eslot = (tid>>2)&3, q = tid&3
    const int n = tid >> 4;
    const int eslot = (tid >> 2) & 3;
    const int q = tid & 3;
    const int node = blk * 32 + n;
    const bool valid = node < N_NODES;
    f32x4 acc = {0.f, 0.f, 0.f, 0.f};
    if (valid) {
        const int s0 = ls32[n];
        const int s1 = s0 + h32[n];
        for (int i = s0 + eslot; i < s1; i += 4) {
            const int s = srt[i] & 32767;
            acc += *(const f32x4*)(h0 + s * HID + q * 4);
        }
    }
#pragma unroll
    for (int c = 0; c < 4; c++) {
        acc[c] += __shfl_xor(acc[c], 4);
        acc[c] += __shfl_xor(acc[c], 8);
    }
    if (valid && eslot == 0) {
        acc += *(const f32x4*)(h0 + node * HID + q * 4);   // self (prescaled)
        accS[n * 17 + q * 4 + 0] = acc[0];
        accS[n * 17 + q * 4 + 1] = acc[1];
        accS[n * 17 + q * 4 + 2] = acc[2];
        accS[n * 17 + q * 4 + 3] = acc[3];
    }
    __syncthreads();
    if (tid < 128) {
        const int n2 = tid >> 2;
        const int node2 = blk * 32 + n2;
        if (node2 < N_NODES) {
            const float dv = rsqrtf((float)(h32[n2] + 1));
            const int q2 = tid & 3;
            float y0 = 0.f, y1 = 0.f, y2 = 0.f, y3 = 0.f;
#pragma unroll
            for (int i = 0; i < 16; i++) {
                const float a = accS[n2 * 17 + i];
                y0 = fmaf(a, w1s[i * 16 + q2 * 4 + 0], y0);
                y1 = fmaf(a, w1s[i * 16 + q2 * 4 + 1], y1);
                y2 = fmaf(a, w1s[i * 16 + q2 * 4 + 2], y2);
                y3 = fmaf(a, w1s[i * 16 + q2 * 4 + 3], y3);
            }
            float d0 = 0.f, d1 = 0.f, d2 = 0.f;
            const float yv[4] = {y0, y1, y2, y3};
#pragma unroll
            for (int j = 0; j < 4; j++) {
                const int o = q2 * 4 + j;
                const float h = fmaxf(b1s[o] + dv * yv[j], 0.f);
                d0 = fmaf(h, w2s[o * 3 + 0], d0);
                d1 = fmaf(h, w2s[o * 3 + 1], d1);
                d2 = fmaf(h, w2s[o * 3 + 2], d2);
            }
            d0 += __shfl_xor(d0, 1); d0 += __shfl_xor(d0, 2);
            d1 += __shfl_xor(d1, 1); d1 += __shfl_xor(d1, 2);
            d2 += __shfl_xor(d2, 1); d2 += __shfl_xor(d2, 2);
            if (q2 == 0) t2p4[node2] = make_float4(d0 * dv, d1 * dv, d2 * dv, dv);
        }
    }
}

// ---------------- K3: agg layer 2 (pre-sorted, no atomics) + log_softmax -----
// 512 threads: 16 lanes/node on the gather.
__global__ __launch_bounds__(512) void agg2_kernel(
    const int* __restrict__ binstart, const int* __restrict__ packed,
    const float4* __restrict__ t2p4, const int* __restrict__ binofs,
    const float* __restrict__ b2g, float* __restrict__ out)
{
    __shared__ int eL[ECAP];
    __shared__ int ofs[64];
    const int tid = threadIdx.x;
    const int blk = blockIdx.x;
    const int beg = binstart[blk];
    const int cnt = binstart[blk + 1] - beg;
    if (tid < 64) ofs[tid] = binofs[blk * 64 + tid];
    for (int j = tid; j < cnt; j += 512) eL[j] = packed[beg + j];
    __syncthreads();
    const int n = tid >> 4;
    const int ln16 = tid & 15;
    const int node = blk * 32 + n;
    float a0 = 0.f, a1 = 0.f, a2 = 0.f;
    if (node < N_NODES) {
        const int s0 = ofs[n];
        const int s1 = s0 + ofs[32 + n];
        for (int i = s0 + ln16; i < s1; i += 16) {
            const int s = eL[i] & 32767;
            const float4 v = t2p4[s];
            a0 += v.x; a1 += v.y; a2 += v.z;
        }
    }
#pragma unroll
    for (int msk = 1; msk < 16; msk <<= 1) {
        a0 += __shfl_xor(a0, msk);
        a1 += __shfl_xor(a1, msk);
        a2 += __shfl_xor(a2, msk);
    }
    if (ln16 == 0 && node < N_NODES) {
        const float4 self = t2p4[node];
        const float dv = self.w;
        const float z0 = b2g[0] + dv * (a0 + self.x);
        const float z1 = b2g[1] + dv * (a1 + self.y);
        const float z2 = b2g[2] + dv * (a2 + self.z);
        const float m = fmaxf(z0, fmaxf(z1, z2));
        const float lg = m + logf(expf(z0 - m) + expf(z1 - m) + expf(z2 - m));
        out[node * 3 + 0] = z0 - lg;
        out[node * 3 + 1] = z1 - lg;
        out[node * 3 + 2] = z2 - lg;
    }
}

extern "C" void kernel_launch(void* const* d_in, const int* in_sizes, int n_in,
                              void* d_out, int out_size, void* d_ws, size_t ws_size,
                              hipStream_t stream)
{
    const float* x   = (const float*)d_in[0];
    const float* w1  = (const float*)d_in[1];
    const float* b1  = (const float*)d_in[2];
    const float* w2  = (const float*)d_in[3];
    const float* b2  = (const float*)d_in[4];
    const float* g1w = (const float*)d_in[5];
    const float* g1b = (const float*)d_in[6];
    const float* g2w = (const float*)d_in[7];
    const float* g2b = (const float*)d_in[8];
    const int*   ei  = (const int*)d_in[9];
    const int* src = ei;
    const int* dst = ei + NEDGE;

    float* ws = (float*)d_ws;
    float*  h0      = ws;                       // 480000 f (prescaled at write)
    float4* t2p4    = (float4*)(ws + 480000);   // 30000 float4 (16B aligned)
    int*    degi    = (int*)(ws + 600000);      // 30000 i
    int*    cntbase = (int*)(ws + 630000);      // 128*938 = 120064 i (blk-major)
    int*    binstart= (int*)(ws + 750064);      // 939 (+pad)
    int*    packed  = (int*)(ws + 751104);      // 960000 i
    int*    binofs  = (int*)(ws + 1711104);     // 938*64 = 60032 i
    short*  bfragsG = (short*)(ws + 1771136);   // 1024 s
    float*  out     = (float*)d_out;

    hipMemsetAsync(degi, 0, N_NODES * sizeof(int), stream);
    hist_kernel<<<HBLK + 1, 512, 0, stream>>>(w2, bfragsG, dst, degi, cntbase);
    conv_reorder<<<HBLK + N_NODES, 256, 0, stream>>>(x, w1, b1, b2, bfragsG,
                                                     src, dst, degi, cntbase,
                                                     packed, binstart, h0);
    agg1_kernel<<<NBIN, 512, 0, stream>>>(binstart, packed, h0,
                                          g1w, g1b, g2w, t2p4, binofs);
    agg2_kernel<<<NBIN, 512, 0, stream>>>(binstart, packed, t2p4, binofs, g2b, out);
}